// Round 2
// 309.446 us; speedup vs baseline: 1.0124x; 1.0124x over previous
//
#include <hip/hip_runtime.h>
#include <hip/hip_bf16.h>
#include <math.h>

// Problem constants
#define NODES   65536
#define DD      128
#define BM      128         // nodes per block: halves W L2 traffic, 24 MFMA per B-triple
#define NST     16          // K stages of 32: X = [h(128)|mem[oth](128)|feat(128)|te(128)]
#define NSUB    24          // 384 N-rows / 16 per subtile
#define WTILE_STRIDE (NSUB * 64 * 8)      // 12288 shorts per W k-tile
#define WG_STRIDE    (20 * WTILE_STRIDE)  // 16 Wih + 4 Whh k-tiles per GRU

typedef __bf16 bf16x8 __attribute__((ext_vector_type(8)));
typedef float  f32x4  __attribute__((ext_vector_type(4)));

static __device__ __forceinline__ unsigned short f2bf(float f) {
    union { float f; unsigned u; } v; v.f = f;
    return (unsigned short)((v.u + 0x8000u) >> 16);      // round-half-up bf16
}
static __device__ __forceinline__ float fastcos(float x) {
    float r = x * 0.15915494309189535f;                   // x / (2*pi)
    r = r - floorf(r);                                    // range-reduce to [0,1)
    return __builtin_amdgcn_cosf(r);                      // v_cos_f32 (revolutions)
}
static __device__ __forceinline__ float fsigmoid(float x) {
    return 1.0f / (1.0f + __expf(-x));
}
static __device__ __forceinline__ float ftanh(float x) {
    float ax = fabsf(x);
    float t  = __expf(-2.0f * ax);
    float th = 1.0f - 2.0f * t / (1.0f + t);
    return copysignf(th, x);
}

// ---------------------------------------------------------------------------
// Kernel 1: pre-swizzle W into per-lane MFMA B-fragment order (bf16) in ws.
//   N-row space n=0..383: [r(128) | z(128) | n-gate(128)].
//   k-tiles 0..15: Wih cols kt*32..+31 ; k-tiles 16..19: Whh cols (kt-16)*32..+31.
//   Wws[((g*20 + kt)*NSUB + t)*512 + lane*8 + j]: n = t*16+(lane&15),
//   k = (lane>>4)*8+j. Each lane's B-frag = one 16 B load, wave = 1 KB coalesced.
// ---------------------------------------------------------------------------
__global__ void prep_w_kernel(const float* __restrict__ Wih0, const float* __restrict__ Whh0,
                              const float* __restrict__ Wih1, const float* __restrict__ Whh1,
                              unsigned short* __restrict__ Wws) {
    int gid = blockIdx.x * 256 + threadIdx.x;
    if (gid >= 2 * WG_STRIDE) return;
    int g   = gid / WG_STRIDE;
    int r   = gid - g * WG_STRIDE;
    int kt  = r / WTILE_STRIDE;
    int r2  = r - kt * WTILE_STRIDE;
    int t   = r2 >> 9;                 // subtile 0..23
    int l8  = r2 & 511;
    int lane = l8 >> 3, j = l8 & 7;
    int cl  = lane & 15, q = lane >> 4;
    int n   = t * 16 + cl;
    const float* Wih = g ? Wih1 : Wih0;
    const float* Whh = g ? Whh1 : Whh0;
    float v;
    if (kt < 16) v = Wih[n * 512 + kt * 32 + q * 8 + j];
    else         v = Whh[n * 128 + (kt - 16) * 32 + q * 8 + j];
    Wws[gid] = f2bf(v);
}

// ---------------------------------------------------------------------------
// Kernel 2: BM=128 tile, XOR-swizzled X (row stride 1024B, byte ^= (row&7)<<4),
// T14-split staging: h+te staged pre-barrier; oth/feat gathers issued into regs
// and hidden under the h/Whh/te MFMA tiles; single write barrier; then the
// oth/feat tiles. 8 waves, each owns N-slice [wv*16, wv*16+16) x M=128.
// ---------------------------------------------------------------------------

// One K-tile: a[8] from X col st*32, 3 (or 6 with Whh pair) B-frags from L2.
#define KTILE_WIH(st)                                                          \
    do {                                                                       \
        bf16x8 a[8];                                                           \
        _Pragma("unroll")                                                      \
        for (int j = 0; j < 8; ++j)                                            \
            a[j] = *(const bf16x8*)(Xb + (j * 16 + cl) * 1024 +                \
                                    (((st) * 64 + q * 16) ^ swz));             \
        const unsigned short* wk = wbase + (size_t)(st) * WTILE_STRIDE;        \
        bf16x8 bR = *(const bf16x8*)(wk + tR * 512);                           \
        bf16x8 bZ = *(const bf16x8*)(wk + tZ * 512);                           \
        bf16x8 bN = *(const bf16x8*)(wk + tN * 512);                           \
        _Pragma("unroll")                                                      \
        for (int j = 0; j < 8; ++j) {                                          \
            acc[j * 4 + 0] = __builtin_amdgcn_mfma_f32_16x16x32_bf16(a[j], bR, acc[j * 4 + 0], 0, 0, 0); \
            acc[j * 4 + 1] = __builtin_amdgcn_mfma_f32_16x16x32_bf16(a[j], bZ, acc[j * 4 + 1], 0, 0, 0); \
            acc[j * 4 + 2] = __builtin_amdgcn_mfma_f32_16x16x32_bf16(a[j], bN, acc[j * 4 + 2], 0, 0, 0); \
        }                                                                      \
    } while (0)

#define KTILE_PAIR(st)                                                         \
    do {                                                                       \
        bf16x8 a[8];                                                           \
        _Pragma("unroll")                                                      \
        for (int j = 0; j < 8; ++j)                                            \
            a[j] = *(const bf16x8*)(Xb + (j * 16 + cl) * 1024 +                \
                                    (((st) * 64 + q * 16) ^ swz));             \
        const unsigned short* wk = wbase + (size_t)(st) * WTILE_STRIDE;        \
        const unsigned short* wh = wbase + (size_t)(16 + (st)) * WTILE_STRIDE; \
        bf16x8 bR = *(const bf16x8*)(wk + tR * 512);                           \
        bf16x8 bZ = *(const bf16x8*)(wk + tZ * 512);                           \
        bf16x8 bN = *(const bf16x8*)(wk + tN * 512);                           \
        bf16x8 cR = *(const bf16x8*)(wh + tR * 512);                           \
        bf16x8 cZ = *(const bf16x8*)(wh + tZ * 512);                           \
        bf16x8 cN = *(const bf16x8*)(wh + tN * 512);                           \
        _Pragma("unroll")                                                      \
        for (int j = 0; j < 8; ++j) {                                          \
            acc[j * 4 + 0] = __builtin_amdgcn_mfma_f32_16x16x32_bf16(a[j], bR, acc[j * 4 + 0], 0, 0, 0); \
            acc[j * 4 + 1] = __builtin_amdgcn_mfma_f32_16x16x32_bf16(a[j], bZ, acc[j * 4 + 1], 0, 0, 0); \
            acc[j * 4 + 2] = __builtin_amdgcn_mfma_f32_16x16x32_bf16(a[j], bN, acc[j * 4 + 2], 0, 0, 0); \
            acc[j * 4 + 0] = __builtin_amdgcn_mfma_f32_16x16x32_bf16(a[j], cR, acc[j * 4 + 0], 0, 0, 0); \
            acc[j * 4 + 1] = __builtin_amdgcn_mfma_f32_16x16x32_bf16(a[j], cZ, acc[j * 4 + 1], 0, 0, 0); \
            acc[j * 4 + 3] = __builtin_amdgcn_mfma_f32_16x16x32_bf16(a[j], cN, acc[j * 4 + 3], 0, 0, 0); \
        }                                                                      \
    } while (0)

__global__ __launch_bounds__(512, 2) void tgn_fused_kernel(
    const int*   __restrict__ n_id,
    const float* __restrict__ memory_,
    const float* __restrict__ pos_mem,
    const float* __restrict__ pos_emb,
    const float* __restrict__ raw_s,
    const float* __restrict__ raw_d,
    const int*   __restrict__ other_s,
    const int*   __restrict__ other_d,
    const int*   __restrict__ t_s,
    const int*   __restrict__ t_d,
    const int*   __restrict__ last_update,
    const float* __restrict__ w_time_mem, const float* __restrict__ b_time_mem,
    const float* __restrict__ w_time_pos, const float* __restrict__ b_time_pos,
    const float* __restrict__ bih_mem, const float* __restrict__ bhh_mem,
    const float* __restrict__ bih_pos, const float* __restrict__ bhh_pos,
    const unsigned short* __restrict__ Wws,
    float* __restrict__ out)
{
    __shared__ __align__(16) unsigned short X[BM * 512];   // 131072 B, swizzled
    __shared__ int   snid[BM];
    __shared__ int   soth[BM];
    __shared__ float sdt[BM];
    __shared__ int   sfeat[BM];

    const int g   = blockIdx.y;
    const int nb  = blockIdx.x;
    const int tid = threadIdx.x;
    const int lane = tid & 63;
    const int wv   = tid >> 6;

    const float* mem_g = g ? pos_mem    : memory_;
    const float* wt    = g ? w_time_pos : w_time_mem;
    const float* bt    = g ? b_time_pos : b_time_mem;
    const float* bih   = g ? bih_pos    : bih_mem;
    const float* bhh   = g ? bhh_pos    : bhh_mem;

    // ---- phase 0: per-node scalars ----
    if (tid < BM) {
        int gi   = nb * BM + tid;
        int id   = n_id[gi];
        int ts   = t_s[gi];
        int td   = t_d[gi];
        bool pick = (ts >= td);
        int oth  = pick ? other_s[gi] : other_d[gi];
        int lu   = last_update[id];
        float dt = (float)(pick ? ts : td) - (float)lu;
        int code;
        if (g) code = pick ? id : other_d[gi];          // row into pos_emb
        else   code = pick ? gi : ~gi;                  // >=0: raw_s row, <0: raw_d row ~code
        snid[tid]  = id;
        soth[tid]  = oth;
        sdt[tid]   = dt;
        sfeat[tid] = code;
        if (g == 0) {
            out[2 * (size_t)NODES * DD + gi] = (float)max(ts, td);   // last_up as fp32
        }
    }
    __syncthreads();

    // ---- stage h (waves 0-3, contiguous rows, fast) + te (waves 4-7, VALU) ----
    {
        int u  = wv & 3;
        int rh = u & 1, ch = u >> 1;
        int row = rh * 64 + lane;
        int swr = (row & 7) << 4;
        char* dst = (char*)X + row * 1024;
        if (wv < 4) {
            const float* src = mem_g + (size_t)snid[row] * DD + ch * 64;
            int colb = ch * 128;                       // byte col within h segment
            #pragma unroll
            for (int i = 0; i < 16; ++i) {
                float4 v = *(const float4*)(src + i * 4);
                ushort4 pv;
                pv.x = f2bf(v.x); pv.y = f2bf(v.y); pv.z = f2bf(v.z); pv.w = f2bf(v.w);
                *(ushort4*)(dst + ((colb + i * 8) ^ swr)) = pv;
            }
        } else {
            float dt = sdt[row];
            const float* wp = wt + ch * 64;
            const float* bp = bt + ch * 64;
            int colb = 768 + ch * 128;                 // te segment bytes
            #pragma unroll
            for (int i = 0; i < 16; ++i) {
                float4 wv4 = *(const float4*)(wp + i * 4);
                float4 bv4 = *(const float4*)(bp + i * 4);
                ushort4 pv;
                pv.x = f2bf(fastcos(dt * wv4.x + bv4.x));
                pv.y = f2bf(fastcos(dt * wv4.y + bv4.y));
                pv.z = f2bf(fastcos(dt * wv4.z + bv4.z));
                pv.w = f2bf(fastcos(dt * wv4.w + bv4.w));
                *(ushort4*)(dst + ((colb + i * 8) ^ swr)) = pv;
            }
        }
    }
    __syncthreads();   // barrier 1: h + te visible

    // ---- K-loop state ----
    f32x4 acc[32];     // [j(m-tile 0..7)][slot 0=r,1=z,2=inn,3=hn]
    #pragma unroll
    for (int i = 0; i < 32; ++i) acc[i] = (f32x4){0.f, 0.f, 0.f, 0.f};

    const int q  = lane >> 4;
    const int cl = lane & 15;
    const int swz = (cl & 7) << 4;
    const unsigned short* wbase = Wws + (size_t)g * WG_STRIDE + lane * 8;
    const int tR = wv, tZ = 8 + wv, tN = 16 + wv;
    const char* Xb = (const char*)X;

    // each wave stages 16 rows of oth + 16 rows of feat (4 lanes x 8 float4/row)
    const int srow = wv * 16 + (lane >> 2);
    const int scol = (lane & 3) * 4;            // float offset, stride 16 floats
    const int sswr = (srow & 7) << 4;
    char* sdst = (char*)X + srow * 1024;

    // ---- issue oth gather (HBM latency hides under the 8 h/Whh tiles) ----
    float4 of[8];
    {
        const float* src = mem_g + (size_t)soth[srow] * DD + scol;
        #pragma unroll
        for (int i = 0; i < 8; ++i) of[i] = *(const float4*)(src + i * 16);
    }
    __builtin_amdgcn_sched_barrier(0);

    // ---- K part 1a: st 0..3 on h cols, Wih + Whh pairs ----
    KTILE_PAIR(0); KTILE_PAIR(1); KTILE_PAIR(2); KTILE_PAIR(3);

    // ---- write oth to LDS (conflict-free under swizzle) ----
    {
        #pragma unroll
        for (int i = 0; i < 8; ++i) {
            ushort4 pv;
            pv.x = f2bf(of[i].x); pv.y = f2bf(of[i].y);
            pv.z = f2bf(of[i].z); pv.w = f2bf(of[i].w);
            *(ushort4*)(sdst + ((256 + scol * 2 + i * 32) ^ sswr)) = pv;
        }
    }

    // ---- issue feat gather (hides under the 4 te tiles) ----
    float4 ff[8];
    {
        const float* src;
        if (g) {
            src = pos_emb + (size_t)sfeat[srow] * DD + scol;
        } else {
            int code = sfeat[srow];
            src = (code >= 0 ? raw_s + (size_t)code * DD
                             : raw_d + (size_t)(~code) * DD) + scol;
        }
        #pragma unroll
        for (int i = 0; i < 8; ++i) ff[i] = *(const float4*)(src + i * 16);
    }
    __builtin_amdgcn_sched_barrier(0);

    // ---- K part 1b: te tiles st 12..15 ----
    KTILE_WIH(12); KTILE_WIH(13); KTILE_WIH(14); KTILE_WIH(15);

    // ---- write feat to LDS ----
    {
        #pragma unroll
        for (int i = 0; i < 8; ++i) {
            ushort4 pv;
            pv.x = f2bf(ff[i].x); pv.y = f2bf(ff[i].y);
            pv.z = f2bf(ff[i].z); pv.w = f2bf(ff[i].w);
            *(ushort4*)(sdst + ((512 + scol * 2 + i * 32) ^ sswr)) = pv;
        }
    }
    __syncthreads();   // barrier 2: oth + feat visible

    // ---- K part 2: st 4..11 (oth, feat cols) ----
    KTILE_WIH(4); KTILE_WIH(5); KTILE_WIH(6); KTILE_WIH(7);
    KTILE_WIH(8); KTILE_WIH(9); KTILE_WIH(10); KTILE_WIH(11);

    // ---- GRU epilogue, in-lane. C/D: col(n)=lane&15, row(m)=q*4+reg ----
    float* outz = out + (size_t)g * NODES * DD;
    const int d = wv * 16 + cl;
    float br  = bih[d]       + bhh[d];
    float bz  = bih[128 + d] + bhh[128 + d];
    float bni = bih[256 + d];
    float bnh = bhh[256 + d];
    #pragma unroll
    for (int j = 0; j < 8; ++j) {
        #pragma unroll
        for (int r = 0; r < 4; ++r) {
            int il = j * 16 + q * 4 + r;                 // node row in block
            float rs  = acc[j * 4 + 0][r] + br;
            float zs  = acc[j * 4 + 1][r] + bz;
            float in_ = acc[j * 4 + 2][r] + bni;
            float hn_ = acc[j * 4 + 3][r] + bnh;
            float rg = fsigmoid(rs);
            float zg = fsigmoid(zs);
            float nv = ftanh(in_ + rg * hn_);
            float h  = mem_g[(size_t)snid[il] * DD + d];
            outz[(size_t)(nb * BM + il) * DD + d] = (1.0f - zg) * nv + zg * h;
        }
    }
}

// ---------------------------------------------------------------------------
extern "C" void kernel_launch(void* const* d_in, const int* in_sizes, int n_in,
                              void* d_out, int out_size, void* d_ws, size_t ws_size,
                              hipStream_t stream) {
    const int*   n_id        = (const int*)  d_in[0];
    const float* memory_     = (const float*)d_in[1];
    const float* pos_mem     = (const float*)d_in[2];
    const float* pos_emb     = (const float*)d_in[3];
    const float* raw_s       = (const float*)d_in[4];
    const float* raw_d       = (const float*)d_in[5];
    const int*   other_s     = (const int*)  d_in[6];
    const int*   other_d     = (const int*)  d_in[7];
    const int*   t_s         = (const int*)  d_in[8];
    const int*   t_d         = (const int*)  d_in[9];
    const int*   last_update = (const int*)  d_in[10];
    const float* w_time_mem  = (const float*)d_in[11];
    const float* b_time_mem  = (const float*)d_in[12];
    const float* w_time_pos  = (const float*)d_in[13];
    const float* b_time_pos  = (const float*)d_in[14];
    const float* Wih_mem     = (const float*)d_in[15];
    const float* Whh_mem     = (const float*)d_in[16];
    const float* bih_mem     = (const float*)d_in[17];
    const float* bhh_mem     = (const float*)d_in[18];
    const float* Wih_pos     = (const float*)d_in[19];
    const float* Whh_pos     = (const float*)d_in[20];
    const float* bih_pos     = (const float*)d_in[21];
    const float* bhh_pos     = (const float*)d_in[22];

    unsigned short* Wws = (unsigned short*)d_ws;   // 2*245760 bf16 = 983 KB
    float* out = (float*)d_out;

    prep_w_kernel<<<(2 * WG_STRIDE + 255) / 256, 256, 0, stream>>>(
        Wih_mem, Whh_mem, Wih_pos, Whh_pos, Wws);

    dim3 grid(NODES / BM, 2);
    tgn_fused_kernel<<<grid, 512, 0, stream>>>(
        n_id, memory_, pos_mem, pos_emb, raw_s, raw_d,
        other_s, other_d, t_s, t_d, last_update,
        w_time_mem, b_time_mem, w_time_pos, b_time_pos,
        bih_mem, bhh_mem, bih_pos, bhh_pos,
        Wws, out);
}